// Round 2
// baseline (291.033 us; speedup 1.0000x reference)
//
#include <hip/hip_runtime.h>
#include <math.h>

namespace {

constexpr int kB   = 64;
constexpr int kCin = 8;
constexpr int kR   = 800;
constexpr int kNC  = 128;
constexpr int kO   = 16;
constexpr int TPB  = 512;
constexpr int NITER = 3;

// LDS overlay: phase-1 staging (2 x 512 x 17 floats = 69.6 KB) is reused in
// phase 2 as the reduction scratch (128x35 + 8x35 + 34 floats = 18.7 KB).
constexpr int SSTRIDE = 17;          // staging row stride (odd -> 2-way bank alias, free)
constexpr int SFLOATS = 512 * SSTRIDE;
constexpr int RSTRIDE = 35;          // reduction row stride (34 cols + 1 pad)

__global__ __launch_bounds__(TPB, 4) void caps_route(
    const float* __restrict__ x, const float* __restrict__ W,
    float* __restrict__ out) {
  __shared__ float lds[2 * SFLOATS];           // 69.6 KB -> 2 blocks/CU
  float* const ldsA = lds;                     // staging b0
  float* const ldsB = lds + SFLOATS;           // staging b1
  float* const red  = lds;                     // phase2: 128 rows x 35
  float* const red2 = lds + 128 * RSTRIDE;     // phase2: 8 rows x 35
  float* const shs  = lds + 136 * RSTRIDE;     // phase2: s0[16],Z0,s1[16],Z1

  const int tid = threadIdx.x;

  // XCD swizzle: 32 blocks sharing c land on one XCD -> W[c] (409.6 KB) stays
  // L2-resident; FETCH_SIZE ~= compulsory 52 MB (verified R1: 32.7 MB).
  const int j   = blockIdx.x;
  const int xcd = j & 7;
  const int k   = j >> 3;                // 0..511
  const int c   = ((k >> 5) << 3) + xcd; // 0..127
  const int bg  = k & 31;
  const int b0  = bg * 2, b1 = b0 + 1;

  float P0[2][kO];   // priors b0: r = tid, tid+512 (second valid iff tid<288)
  float P1[2][kO];   // priors b1

  const float* Wc  = W + (size_t)c * kR * kCin * kO;
  const float* x0p = x + (size_t)b0 * kCin * kR;
  const float* x1p = x + (size_t)b1 * kCin * kR;

  // ---------------- Phase 1: priors ----------------
  // Unit (r, oc): 4 lanes w/ consecutive oc read one 64B line of W per i
  // (perfect coalescing); results staged to LDS, picked up by owning thread.
  const int oc = tid & 3;
  {  // T = 0: rows 0..511
    #pragma unroll
    for (int s = 0; s < 4; ++s) {
      const int rl = s * 128 + (tid >> 2);
      float xv0[kCin], xv1[kCin];
      #pragma unroll
      for (int i = 0; i < kCin; ++i) {
        xv0[i] = x0p[i * kR + rl];
        xv1[i] = x1p[i * kR + rl];
      }
      const float4* Wr = reinterpret_cast<const float4*>(Wc + (size_t)rl * kCin * kO);
      float4 a0 = make_float4(0.f, 0.f, 0.f, 0.f);
      float4 a1 = make_float4(0.f, 0.f, 0.f, 0.f);
      #pragma unroll
      for (int i = 0; i < kCin; ++i) {
        const float4 w = Wr[i * 4 + oc];
        a0.x += xv0[i] * w.x; a0.y += xv0[i] * w.y;
        a0.z += xv0[i] * w.z; a0.w += xv0[i] * w.w;
        a1.x += xv1[i] * w.x; a1.y += xv1[i] * w.y;
        a1.z += xv1[i] * w.z; a1.w += xv1[i] * w.w;
      }
      const int base = rl * SSTRIDE + oc * 4;
      ldsA[base + 0] = a0.x; ldsA[base + 1] = a0.y;
      ldsA[base + 2] = a0.z; ldsA[base + 3] = a0.w;
      ldsB[base + 0] = a1.x; ldsB[base + 1] = a1.y;
      ldsB[base + 2] = a1.z; ldsB[base + 3] = a1.w;
    }
    __syncthreads();
    #pragma unroll
    for (int o = 0; o < kO; ++o) {
      P0[0][o] = ldsA[tid * SSTRIDE + o];
      P1[0][o] = ldsB[tid * SSTRIDE + o];
    }
    __syncthreads();
  }
  {  // T = 1: rows 512..799 (288 rows)
    #pragma unroll
    for (int s = 0; s < 3; ++s) {
      const int rl = s * 128 + (tid >> 2);
      const int r  = 512 + rl;
      if (r < kR) {
        float xv0[kCin], xv1[kCin];
        #pragma unroll
        for (int i = 0; i < kCin; ++i) {
          xv0[i] = x0p[i * kR + r];
          xv1[i] = x1p[i * kR + r];
        }
        const float4* Wr = reinterpret_cast<const float4*>(Wc + (size_t)r * kCin * kO);
        float4 a0 = make_float4(0.f, 0.f, 0.f, 0.f);
        float4 a1 = make_float4(0.f, 0.f, 0.f, 0.f);
        #pragma unroll
        for (int i = 0; i < kCin; ++i) {
          const float4 w = Wr[i * 4 + oc];
          a0.x += xv0[i] * w.x; a0.y += xv0[i] * w.y;
          a0.z += xv0[i] * w.z; a0.w += xv0[i] * w.w;
          a1.x += xv1[i] * w.x; a1.y += xv1[i] * w.y;
          a1.z += xv1[i] * w.z; a1.w += xv1[i] * w.w;
        }
        const int base = rl * SSTRIDE + oc * 4;
        ldsA[base + 0] = a0.x; ldsA[base + 1] = a0.y;
        ldsA[base + 2] = a0.z; ldsA[base + 3] = a0.w;
        ldsB[base + 0] = a1.x; ldsB[base + 1] = a1.y;
        ldsB[base + 2] = a1.z; ldsB[base + 3] = a1.w;
      }
    }
    __syncthreads();
    if (tid < kR - 512) {
      #pragma unroll
      for (int o = 0; o < kO; ++o) {
        P0[1][o] = ldsA[tid * SSTRIDE + o];
        P1[1][o] = ldsB[tid * SSTRIDE + o];
      }
    }
    __syncthreads();   // staging buffer dead; red region safe to write
  }

  // ---------------- Phase 2: routing, b0+b1 fused ----------------
  // No max-subtraction: logits start at 0 and |delta| <~ 15/iter over 2
  // updates -> exp stays comfortably inside fp32 range.
  const bool v2     = (tid < kR - 512);
  const int  lane   = tid & 63;
  const int  redrow = (tid >> 6) * 16 + (lane >> 2);

  float l0[2] = {0.f, 0.f}, l1[2] = {0.f, 0.f};

  #pragma unroll
  for (int it = 0; it < NITER; ++it) {
    // -- partial s[16]+Z per b, 4-lane shuffle reduce, write to red --
    {
      float sp[kO + 1];
      #pragma unroll
      for (int v = 0; v <= kO; ++v) sp[v] = 0.f;
      #pragma unroll
      for (int jj = 0; jj < 2; ++jj) {
        if (jj == 0 || v2) {
          const float e = (it == 0) ? 1.f : __expf(l0[jj]);
          sp[kO] += e;
          #pragma unroll
          for (int o = 0; o < kO; ++o) sp[o] += e * P0[jj][o];
        }
      }
      #pragma unroll
      for (int v = 0; v <= kO; ++v) {
        sp[v] += __shfl_xor(sp[v], 1, 64);
        sp[v] += __shfl_xor(sp[v], 2, 64);
      }
      if ((lane & 3) == 0) {
        #pragma unroll
        for (int v = 0; v <= kO; ++v) red[redrow * RSTRIDE + v] = sp[v];
      }
    }
    {
      float sp[kO + 1];
      #pragma unroll
      for (int v = 0; v <= kO; ++v) sp[v] = 0.f;
      #pragma unroll
      for (int jj = 0; jj < 2; ++jj) {
        if (jj == 0 || v2) {
          const float e = (it == 0) ? 1.f : __expf(l1[jj]);
          sp[kO] += e;
          #pragma unroll
          for (int o = 0; o < kO; ++o) sp[o] += e * P1[jj][o];
        }
      }
      #pragma unroll
      for (int v = 0; v <= kO; ++v) {
        sp[v] += __shfl_xor(sp[v], 1, 64);
        sp[v] += __shfl_xor(sp[v], 2, 64);
      }
      if ((lane & 3) == 0) {
        #pragma unroll
        for (int v = 0; v <= kO; ++v) red[redrow * RSTRIDE + 17 + v] = sp[v];
      }
    }
    __syncthreads();

    // -- tree: 128 rows -> 8 rows (272 threads) -> 1 row (34 threads) --
    if (tid < 272) {
      const int q = tid / 34, col = tid - q * 34;
      float a = 0.f;
      #pragma unroll
      for (int rr = 0; rr < 16; ++rr) a += red[(q * 16 + rr) * RSTRIDE + col];
      red2[q * RSTRIDE + col] = a;
    }
    __syncthreads();
    if (tid < 34) {
      float a = 0.f;
      #pragma unroll
      for (int q = 0; q < 8; ++q) a += red2[q * RSTRIDE + tid];
      shs[tid] = a;
    }
    __syncthreads();

    // -- squash (redundant per thread) + logit update / output --
    const float Zi0 = 1.f / shs[16];
    const float Zi1 = 1.f / shs[33];
    float sv0[kO], sv1[kO], sn0 = 0.f, sn1 = 0.f;
    #pragma unroll
    for (int o = 0; o < kO; ++o) {
      sv0[o] = shs[o] * Zi0;       sn0 += sv0[o] * sv0[o];
      sv1[o] = shs[17 + o] * Zi1;  sn1 += sv1[o] * sv1[o];
    }
    const float fac0 = sqrtf(sn0) / (1.f + sn0);
    const float fac1 = sqrtf(sn1) / (1.f + sn1);

    if (it < NITER - 1) {
      #pragma unroll
      for (int jj = 0; jj < 2; ++jj) {
        if (jj == 0 || v2) {
          float d0 = 0.f, d1 = 0.f;
          #pragma unroll
          for (int o = 0; o < kO; ++o) {
            d0 += P0[jj][o] * sv0[o];
            d1 += P1[jj][o] * sv1[o];
          }
          l0[jj] += d0 * fac0;
          l1[jj] += d1 * fac1;
        }
      }
    } else {
      // out[b, o, c], shape [B, O, NC]
      if (tid < kO) {
        out[(size_t)b0 * kO * kNC + tid * kNC + c] = sv0[tid] * fac0;
      } else if (tid < 2 * kO) {
        out[(size_t)b1 * kO * kNC + (tid - kO) * kNC + c] = sv1[tid - kO] * fac1;
      }
    }
  }
}

}  // namespace

extern "C" void kernel_launch(void* const* d_in, const int* in_sizes, int n_in,
                              void* d_out, int out_size, void* d_ws, size_t ws_size,
                              hipStream_t stream) {
  const float* x = (const float*)d_in[0];          // [64, 8, 800] fp32
  const float* W = (const float*)d_in[1];          // [128, 800, 8, 16] fp32
  float* out = (float*)d_out;                      // [64, 16, 128] fp32
  (void)in_sizes; (void)n_in; (void)out_size; (void)d_ws; (void)ws_size;
  const int grid = kNC * (kB / 2);                 // 4096 blocks: (c, b-pair)
  caps_route<<<dim3(grid), dim3(TPB), 0, stream>>>(x, W, out);
}